// Round 2
// baseline (251.474 us; speedup 1.0000x reference)
//
#include <hip/hip_runtime.h>

// RoPE3D encoder: cos/sin tables for (T=32, H=64, W=64), DIM=192.
// Output: [cos (N*192 f32)] ++ [sin (N*192 f32)], N = 131072. 192 MiB total.
// Pure write-bound kernel. All transcendentals via raw HW ops in the
// revolution domain (v_exp_f32 / v_fract_f32 / v_sin_f32 / v_cos_f32).
//
// R2 change vs baseline: PERSISTENT GRID-STRIDE. 2048 blocks (8 waves/SIMD,
// one resident generation) x 12 fully-unrolled groups/thread, instead of
// 24,576 blocks of single-shot waves. Theory: 98k short-lived waves each pay
// a full store-drain (s_waitcnt vmcnt(0) before s_endpgm) against only 2 KiB
// of traffic -> wave-churn limits effective write BW to ~1.7 TB/s (4x under
// the 6.6 TB/s the poison fill achieves on the same buffer). Persistent waves
// keep ~24 stores in flight and pay ONE terminal drain.
// Stores reverted to plain float4 (nt was null in R1).

#define NPOS (32 * 64 * 64)   // 131072
#define DIM 192
#define TOTAL4 (NPOS * 48u)   // 6,291,456 float4-groups
#define NBLOCKS 2048u
#define NTHREADS (NBLOCKS * 256u)   // 524,288
#define ITERS (TOTAL4 / NTHREADS)   // 12, exact

// -log2(10000)/32  (per-index freq exponent step)
#define NEG_C (-0.41524101186092027f)
// log2(1/(2*pi))  (convert radians-freq to revolutions-freq)
#define LOG2_INV_2PI (-2.6514961294723187f)
// 10000^(-1/32), ^(-2/32), ^(-3/32): ratios between adjacent freqs
#define R1 0.7498942093324559f
#define R2 0.5623413251903491f
#define R3 0.4216965034285822f

__global__ __launch_bounds__(256) void rope3d_kernel(float* __restrict__ out) {
    unsigned int i = blockIdx.x * 256u + threadIdx.x;   // float4-group id

#pragma unroll
    for (unsigned int it = 0; it < ITERS; ++it, i += NTHREADS) {
        const unsigned int r = i / 48u;                 // row (position)
        const unsigned int c = i - r * 48u;             // float4 col [0,48)

        // position decode (all pow-2): r = ((t*64)+h)*64 + w
        const unsigned int t = r >> 12;
        const unsigned int h = (r >> 6) & 63u;
        const unsigned int w = r & 63u;

        // axis constant across the 4 features (seg boundaries 64/128 are %4==0)
        const unsigned int axis = c >> 4;               // 0:w 1:h 2:t
        const float pos = (float)(axis == 0 ? w : (axis == 1 ? h : t));

        // base frequency (revolutions/position) for this thread's first feature
        const unsigned int inner0 = (c * 4u) & 31u;
        const float fr0 = __builtin_exp2f(fmaf((float)inner0, NEG_C, LOG2_INV_2PI));
        const float fr1 = fr0 * R1;
        const float fr2 = fr0 * R2;
        const float fr3 = fr0 * R3;

        // angles in revolutions, range-reduced to [0,1) before v_sin/v_cos
        const float a0 = __builtin_amdgcn_fractf(pos * fr0);
        const float a1 = __builtin_amdgcn_fractf(pos * fr1);
        const float a2 = __builtin_amdgcn_fractf(pos * fr2);
        const float a3 = __builtin_amdgcn_fractf(pos * fr3);

        const float c0 = __builtin_amdgcn_cosf(a0);
        const float c1 = __builtin_amdgcn_cosf(a1);
        const float c2 = __builtin_amdgcn_cosf(a2);
        const float c3 = __builtin_amdgcn_cosf(a3);
        const float s0 = __builtin_amdgcn_sinf(a0);
        const float s1 = __builtin_amdgcn_sinf(a1);
        const float s2 = __builtin_amdgcn_sinf(a2);
        const float s3 = __builtin_amdgcn_sinf(a3);

        const size_t base = (size_t)i * 4u;             // contiguous per wave
        *(float4*)(out + base) = make_float4(c0, c1, c2, c3);
        *(float4*)(out + (size_t)NPOS * DIM + base) = make_float4(s0, s1, s2, s3);
    }
}

extern "C" void kernel_launch(void* const* d_in, const int* in_sizes, int n_in,
                              void* d_out, int out_size, void* d_ws, size_t ws_size,
                              hipStream_t stream) {
    (void)d_in; (void)in_sizes; (void)n_in; (void)d_ws; (void)ws_size; (void)out_size;
    float* out = (float*)d_out;
    rope3d_kernel<<<NBLOCKS, 256, 0, stream>>>(out);
}

// Round 3
// 243.164 us; speedup vs baseline: 1.0342x; 1.0342x over previous
//
#include <hip/hip_runtime.h>

// RoPE3D encoder: cos/sin tables for (T=32, H=64, W=64), DIM=192.
// Output: [cos (N*192 f32)] ++ [sin (N*192 f32)], N = 131072. 192 MiB total.
// Pure write-bound kernel. All transcendentals via raw HW ops in the
// revolution domain (v_exp_f32 / v_fract_f32 / v_sin_f32 / v_cos_f32).
//
// R3 change: ONE STORE STREAM PER WAVE. Previously every wave issued two
// lockstep store streams offset by exactly 96 MiB (cos at base, sin at
// base+0x6000000) — a candidate for HBM channel-hash aliasing (both streams
// hit the same channel phase every cycle). Now: 2x threads; even waves write
// only cos, odd waves write only sin. Same 1 KiB-contiguous-per-wave
// coalescing, one 16 B store per thread, and each thread computes only the
// trans ops it stores (4 cos OR 4 sin). Math otherwise identical to the
// 242.9 µs baseline. Nulls so far: nt stores (R1), persistent waves (R2).

#define NPOS (32 * 64 * 64)   // 131072
#define DIM 192
#define TOTAL4 (NPOS * 48u)   // 6,291,456 float4-groups

// -log2(10000)/32  (per-index freq exponent step)
#define NEG_C (-0.41524101186092027f)
// log2(1/(2*pi))  (convert radians-freq to revolutions-freq)
#define LOG2_INV_2PI (-2.6514961294723187f)
// 10000^(-1/32), ^(-2/32), ^(-3/32): ratios between adjacent freqs
#define R1 0.7498942093324559f
#define R2 0.5623413251903491f
#define R3 0.4216965034285822f

__global__ __launch_bounds__(256) void rope3d_kernel(float* __restrict__ out) {
    const unsigned int tid = blockIdx.x * 256u + threadIdx.x;
    const unsigned int wave = tid >> 6;
    const unsigned int lane = tid & 63u;
    const unsigned int is_sin = wave & 1u;            // even wave: cos, odd: sin
    const unsigned int i = (wave >> 1) * 64u + lane;  // float4-group id [0, TOTAL4)

    const unsigned int r = i / 48u;                   // row (position)
    const unsigned int c = i - r * 48u;               // float4 col [0,48)

    // position decode (all pow-2): r = ((t*64)+h)*64 + w
    const unsigned int t = r >> 12;
    const unsigned int h = (r >> 6) & 63u;
    const unsigned int w = r & 63u;

    // axis constant across the 4 features (seg boundaries 64/128 are %4==0)
    const unsigned int axis = c >> 4;                 // 0:w 1:h 2:t
    const float pos = (float)(axis == 0 ? w : (axis == 1 ? h : t));

    // base frequency (revolutions/position) for this thread's first feature
    const unsigned int inner0 = (c * 4u) & 31u;
    const float fr0 = __builtin_exp2f(fmaf((float)inner0, NEG_C, LOG2_INV_2PI));
    const float fr1 = fr0 * R1;
    const float fr2 = fr0 * R2;
    const float fr3 = fr0 * R3;

    // angles in revolutions, range-reduced to [0,1) before v_sin/v_cos
    const float a0 = __builtin_amdgcn_fractf(pos * fr0);
    const float a1 = __builtin_amdgcn_fractf(pos * fr1);
    const float a2 = __builtin_amdgcn_fractf(pos * fr2);
    const float a3 = __builtin_amdgcn_fractf(pos * fr3);

    float v0, v1, v2, v3;
    if (is_sin) {
        v0 = __builtin_amdgcn_sinf(a0);
        v1 = __builtin_amdgcn_sinf(a1);
        v2 = __builtin_amdgcn_sinf(a2);
        v3 = __builtin_amdgcn_sinf(a3);
    } else {
        v0 = __builtin_amdgcn_cosf(a0);
        v1 = __builtin_amdgcn_cosf(a1);
        v2 = __builtin_amdgcn_cosf(a2);
        v3 = __builtin_amdgcn_cosf(a3);
    }

    // one contiguous 1 KiB run per wave, single stream
    const size_t base = (size_t)is_sin * ((size_t)NPOS * DIM) + (size_t)i * 4u;
    *(float4*)(out + base) = make_float4(v0, v1, v2, v3);
}

extern "C" void kernel_launch(void* const* d_in, const int* in_sizes, int n_in,
                              void* d_out, int out_size, void* d_ws, size_t ws_size,
                              hipStream_t stream) {
    (void)d_in; (void)in_sizes; (void)n_in; (void)d_ws; (void)ws_size; (void)out_size;
    float* out = (float*)d_out;
    const unsigned int total_threads = TOTAL4 * 2u;       // 12,582,912
    const unsigned int blocks = total_threads / 256u;     // 49,152, exact
    rope3d_kernel<<<blocks, 256, 0, stream>>>(out);
}